// Round 6
// baseline (230.227 us; speedup 1.0000x reference)
//
#include <hip/hip_runtime.h>
#include <math.h>

#define D_MODEL 1024
#define NHEAD   16
#define DKH     64
#define SEQ     2048
#define BATCH   2
#define TOK     (BATCH*SEQ)   // 4096

typedef short s16x8 __attribute__((ext_vector_type(8)));
typedef float f32x4 __attribute__((ext_vector_type(4)));
typedef unsigned short ushort_t;

__device__ inline unsigned short f2bf(float f) {
    union { float f; unsigned u; } v; v.f = f;
    unsigned r = v.u + 0x7FFFu + ((v.u >> 16) & 1u);   // RNE
    return (unsigned short)(r >> 16);
}
__device__ inline float bf2f(ushort_t h) {
    union { unsigned u; float f; } v; v.u = (unsigned)h << 16;
    return v.f;
}
__device__ inline unsigned cvt_pk_bf16(float a, float b) {  // low16=bf16(a), high16=bf16(b)
    unsigned r;
    asm("v_cvt_pk_bf16_f32 %0, %1, %2" : "=v"(r) : "v"(a), "v"(b));
    return r;
}
__device__ inline void gload16(const void* g, void* l) {
    __builtin_amdgcn_global_load_lds(
        (const __attribute__((address_space(1))) void*)g,
        (__attribute__((address_space(3))) void*)l, 16, 0, 0);
}

// ---------------------------------------------------------------------------
// Weights fp32->bf16 (Wo as hi+lo split) + mask -> float bias (-1e9 / 0).
// ---------------------------------------------------------------------------
__global__ __launch_bounds__(256) void convert_w(
    const float* __restrict__ Wq, const float* __restrict__ Wk,
    const float* __restrict__ Wv, const float* __restrict__ Wo,
    const int* __restrict__ mask,
    ushort_t* __restrict__ Wqb, ushort_t* __restrict__ Wkb,
    ushort_t* __restrict__ Wvb, ushort_t* __restrict__ Wohi,
    ushort_t* __restrict__ Wolo, float* __restrict__ mb)
{
    const int W4 = D_MODEL * D_MODEL / 4;   // 262144
    const int total = 4 * W4 + TOK / 4;
    for (int u = blockIdx.x * 256 + threadIdx.x; u < total; u += gridDim.x * 256) {
        if (u < 3 * W4) {
            int which = u / W4, off = u - which * W4;
            const float* src = which == 0 ? Wq : which == 1 ? Wk : Wv;
            ushort_t*    dst = which == 0 ? Wqb : which == 1 ? Wkb : Wvb;
            float4 f = ((const float4*)src)[off];
            uint2 o;
            o.x = cvt_pk_bf16(f.x, f.y);
            o.y = cvt_pk_bf16(f.z, f.w);
            ((uint2*)dst)[off] = o;
        } else if (u < 4 * W4) {
            int off = u - 3 * W4;
            float4 f = ((const float4*)Wo)[off];
            ushort_t h0 = f2bf(f.x), h1 = f2bf(f.y), h2 = f2bf(f.z), h3 = f2bf(f.w);
            uint2 hw;
            hw.x = (unsigned)h0 | ((unsigned)h1 << 16);
            hw.y = (unsigned)h2 | ((unsigned)h3 << 16);
            ((uint2*)Wohi)[off] = hw;
            uint2 lw;
            lw.x = cvt_pk_bf16(f.x - bf2f(h0), f.y - bf2f(h1));
            lw.y = cvt_pk_bf16(f.z - bf2f(h2), f.w - bf2f(h3));
            ((uint2*)Wolo)[off] = lw;
        } else {
            int off = u - 4 * W4;
            int4 m = ((const int4*)mask)[off];
            float4 f;
            f.x = m.x ? 0.f : -1e9f;
            f.y = m.y ? 0.f : -1e9f;
            f.z = m.z ? 0.f : -1e9f;
            f.w = m.w ? 0.f : -1e9f;
            ((float4*)mb)[off] = f;
        }
    }
}

// ---------------------------------------------------------------------------
// bf16 MFMA GEMM: C[TOK][D] = A @ W^T + bias.  BM=128 BN=128 BK=32, 256 thr,
// 4 waves, wave-tile 64x64 (4x4 fragments, 16 MFMA/K-step)  [m97 structure].
// AFP32:   A is fp32, converted to bf16 during reg-staging.
// OUTMODE: 0 = bf16 row-major, 1 = fp32 row-major, 2 = bf16 transposed per-head
//          into [b][h][d][s] (two 64-col half-transposes via LDS).
// SPLITW:  C = A*(W + W2)^T  (hi/lo weight split for fp32-grade accuracy).
// ---------------------------------------------------------------------------
template<int AFP32, int OUTMODE, int SPLITW>
__global__ __launch_bounds__(256) void gemm3(
    const void* __restrict__ Ain, const ushort_t* __restrict__ Wptr,
    const ushort_t* __restrict__ W2ptr, const float* __restrict__ bias,
    void* __restrict__ Cout)
{
    constexpr int BASE = 128*32*2 + 128*32*2 + (SPLITW ? 128*32*2 : 0);
    constexpr int PSZ  = (OUTMODE == 2 && 64*136*2 > BASE) ? 64*136*2 : BASE;
    __shared__ __align__(16) char pool[PSZ];
    ushort_t* As  = (ushort_t*)pool;
    ushort_t* Ws  = As + 128*32;
    ushort_t* Ws2 = Ws + 128*32;

    const int t = threadIdx.x;
    const int w = t >> 6, lane = t & 63, l15 = lane & 15, l4 = lane >> 4;
    const int m0 = blockIdx.y * 128, n0 = blockIdx.x * 128;
    const int wr = w >> 1, wc = w & 1;

    f32x4 acc[4][4];
#pragma unroll
    for (int m = 0; m < 4; ++m)
#pragma unroll
        for (int n = 0; n < 4; ++n) acc[m][n] = (f32x4){0.f, 0.f, 0.f, 0.f};

    const ushort_t* Wg = Wptr + (size_t)(n0 + (t >> 2)) * D_MODEL + (t & 3) * 8;
    ushort_t* WsW = Ws + w * 512;
    const ushort_t* Ag16 = (const ushort_t*)Ain + (size_t)(m0 + (t >> 2)) * D_MODEL + (t & 3) * 8;
    ushort_t* AsW = As + w * 512;
    const float* Ag32 = (const float*)Ain + (size_t)(m0 + (t >> 1)) * D_MODEL + (t & 1) * 16;

    for (int k0 = 0; k0 < D_MODEL; k0 += 32) {
        __syncthreads();
        if constexpr (AFP32) {
            const float4* ap = (const float4*)(Ag32 + k0);
            float4 f0 = ap[0], f1 = ap[1], f2 = ap[2], f3 = ap[3];
            uint4 u0, u1;
            u0.x = cvt_pk_bf16(f0.x, f0.y); u0.y = cvt_pk_bf16(f0.z, f0.w);
            u0.z = cvt_pk_bf16(f1.x, f1.y); u0.w = cvt_pk_bf16(f1.z, f1.w);
            u1.x = cvt_pk_bf16(f2.x, f2.y); u1.y = cvt_pk_bf16(f2.z, f2.w);
            u1.z = cvt_pk_bf16(f3.x, f3.y); u1.w = cvt_pk_bf16(f3.z, f3.w);
            uint4* dst = (uint4*)&As[(t >> 1) * 32 + (t & 1) * 16];
            dst[0] = u0; dst[1] = u1;
        } else {
            gload16(Ag16 + k0, AsW);
            gload16(Ag16 + (size_t)64 * D_MODEL + k0, AsW + 2048);
        }
        gload16(Wg + k0, WsW);
        gload16(Wg + (size_t)64 * D_MODEL + k0, WsW + 2048);
        if constexpr (SPLITW) {
            const ushort_t* W2g = W2ptr + (size_t)(n0 + (t >> 2)) * D_MODEL + (t & 3) * 8;
            gload16(W2g + k0, Ws2 + w * 512);
            gload16(W2g + (size_t)64 * D_MODEL + k0, Ws2 + w * 512 + 2048);
        }
        __syncthreads();

        s16x8 af[4], bfr[4];
#pragma unroll
        for (int m = 0; m < 4; ++m)
            af[m] = *(const s16x8*)&As[(wr * 64 + m * 16 + l15) * 32 + l4 * 8];
#pragma unroll
        for (int n = 0; n < 4; ++n)
            bfr[n] = *(const s16x8*)&Ws[(wc * 64 + n * 16 + l15) * 32 + l4 * 8];
        if constexpr (SPLITW) {
            s16x8 bfr2[4];
#pragma unroll
            for (int n = 0; n < 4; ++n)
                bfr2[n] = *(const s16x8*)&Ws2[(wc * 64 + n * 16 + l15) * 32 + l4 * 8];
#pragma unroll
            for (int m = 0; m < 4; ++m)
#pragma unroll
                for (int n = 0; n < 4; ++n) {
                    acc[m][n] = __builtin_amdgcn_mfma_f32_16x16x32_bf16(af[m], bfr[n],  acc[m][n], 0, 0, 0);
                    acc[m][n] = __builtin_amdgcn_mfma_f32_16x16x32_bf16(af[m], bfr2[n], acc[m][n], 0, 0, 0);
                }
        } else {
#pragma unroll
            for (int m = 0; m < 4; ++m)
#pragma unroll
                for (int n = 0; n < 4; ++n)
                    acc[m][n] = __builtin_amdgcn_mfma_f32_16x16x32_bf16(af[m], bfr[n], acc[m][n], 0, 0, 0);
        }
    }

    if constexpr (OUTMODE == 2) {
        // transpose per 64-col half (one head each) through LDS, coalesced out
        ushort_t* Ct = (ushort_t*)pool;   // [64][136]
        const int h0 = blockIdx.x * 2;
        const int bb = m0 >> 11;
        const int s0 = m0 & (SEQ - 1);
#pragma unroll
        for (int hh = 0; hh < 2; ++hh) {
            __syncthreads();
            if (wc == hh) {
#pragma unroll
                for (int n = 0; n < 4; ++n) {
                    const int nl = n * 16 + l15;            // 0..63 within half
                    const float bv = bias[n0 + hh * 64 + nl];
#pragma unroll
                    for (int m = 0; m < 4; ++m) {
                        const int ml = wr * 64 + m * 16 + l4 * 4;
#pragma unroll
                        for (int r = 0; r < 4; ++r)
                            Ct[nl * 136 + ml + r] = f2bf(acc[m][n][r] + bv);
                    }
                }
            }
            __syncthreads();
            const int dl = t >> 2;   // 0..63 (d within head)
            ushort_t* dst = (ushort_t*)Cout + (((size_t)bb * NHEAD + h0 + hh) * DKH + dl) * SEQ + s0;
#pragma unroll
            for (int c = 0; c < 4; ++c) {
                int chk = (t & 3) + c * 4;   // 16 chunks of 8 -> 128 tokens
                *(uint4*)&dst[chk * 8] = *(const uint4*)&Ct[dl * 136 + chk * 8];
            }
        }
    } else {
#pragma unroll
        for (int n = 0; n < 4; ++n) {
            const int col = n0 + wc * 64 + n * 16 + l15;
            const float bv = bias[col];
#pragma unroll
            for (int m = 0; m < 4; ++m) {
                const int row = m0 + wr * 64 + m * 16 + l4 * 4;
#pragma unroll
                for (int r = 0; r < 4; ++r) {
                    float val = acc[m][n][r] + bv;
                    if constexpr (OUTMODE == 0)
                        ((ushort_t*)Cout)[(size_t)(row + r) * D_MODEL + col] = f2bf(val);
                    else
                        ((float*)Cout)[(size_t)(row + r) * D_MODEL + col] = val;
                }
            }
        }
    }
}

// ---------------------------------------------------------------------------
// Flash attention (verified round-4 version, byte-identical): bf16 MFMA,
// no online-max (scores provably bounded), V pre-transposed in global.
// ---------------------------------------------------------------------------
__global__ __launch_bounds__(256) void flash2(
    const ushort_t* __restrict__ Q, const ushort_t* __restrict__ K,
    const ushort_t* __restrict__ Vt, const float* __restrict__ mb,
    ushort_t* __restrict__ Ctx)
{
    __shared__ ushort_t Ks[64 * 72];
    __shared__ ushort_t Vs[64 * 72];
    __shared__ ushort_t Ps[64 * 72];

    const int t = threadIdx.x;
    const int w = t >> 6, lane = t & 63, l15 = lane & 15, l4 = lane >> 4;
    const int q0 = blockIdx.x * 64;
    const int bh = blockIdx.y, b = bh >> 4, h = bh & 15;

    s16x8 qf0, qf1;
    {
        const ushort_t* qp = Q + ((size_t)b * SEQ + q0 + w * 16 + l15) * D_MODEL + h * DKH + l4 * 8;
        qf0 = *(const s16x8*)qp;
        qf1 = *(const s16x8*)(qp + 32);
    }

    f32x4 oacc[4];
#pragma unroll
    for (int dt = 0; dt < 4; ++dt) oacc[dt] = (f32x4){0.f, 0.f, 0.f, 0.f};
    float lpart[4] = {0.f, 0.f, 0.f, 0.f};

    const int ch   = t & 7;
    const int row0 = t >> 3;
    const ushort_t* Kg = K  + ((size_t)b * SEQ) * D_MODEL + h * DKH + ch * 8;
    const ushort_t* Vg = Vt + ((size_t)bh * DKH) * SEQ + ch * 8;

    uint4 kr0 = *(const uint4*)&Kg[(size_t)row0 * D_MODEL];
    uint4 kr1 = *(const uint4*)&Kg[(size_t)(row0 + 32) * D_MODEL];
    uint4 vr0 = *(const uint4*)&Vg[(size_t)row0 * SEQ];
    uint4 vr1 = *(const uint4*)&Vg[(size_t)(row0 + 32) * SEQ];

    const float CSC = 0.18033688011112042f;   // 0.125 * log2(e)
    const float* mbp = mb + b * SEQ;

    for (int k0 = 0; k0 < SEQ; k0 += 64) {
        __syncthreads();
        *(uint4*)&Ks[row0 * 72 + ch * 8]        = kr0;
        *(uint4*)&Ks[(row0 + 32) * 72 + ch * 8] = kr1;
        *(uint4*)&Vs[row0 * 72 + ch * 8]        = vr0;
        *(uint4*)&Vs[(row0 + 32) * 72 + ch * 8] = vr1;
        __syncthreads();
        if (k0 + 64 < SEQ) {
            kr0 = *(const uint4*)&Kg[(size_t)(k0 + 64 + row0) * D_MODEL];
            kr1 = *(const uint4*)&Kg[(size_t)(k0 + 64 + row0 + 32) * D_MODEL];
            vr0 = *(const uint4*)&Vg[(size_t)row0 * SEQ + k0 + 64];
            vr1 = *(const uint4*)&Vg[(size_t)(row0 + 32) * SEQ + k0 + 64];
        }
        float mbv[4];
#pragma unroll
        for (int ct = 0; ct < 4; ++ct) mbv[ct] = mbp[k0 + ct * 16 + l15];

        f32x4 sacc[4];
#pragma unroll
        for (int ct = 0; ct < 4; ++ct) sacc[ct] = (f32x4){0.f, 0.f, 0.f, 0.f};
#pragma unroll
        for (int ct = 0; ct < 4; ++ct) {
            s16x8 b0 = *(const s16x8*)&Ks[(ct * 16 + l15) * 72 + l4 * 8];
            s16x8 b1 = *(const s16x8*)&Ks[(ct * 16 + l15) * 72 + 32 + l4 * 8];
            sacc[ct] = __builtin_amdgcn_mfma_f32_16x16x32_bf16(qf0, b0, sacc[ct], 0, 0, 0);
            sacc[ct] = __builtin_amdgcn_mfma_f32_16x16x32_bf16(qf1, b1, sacc[ct], 0, 0, 0);
        }

#pragma unroll
        for (int ct = 0; ct < 4; ++ct) {
            float p0 = __builtin_amdgcn_exp2f(fmaf(sacc[ct][0], CSC, mbv[ct]));
            float p1 = __builtin_amdgcn_exp2f(fmaf(sacc[ct][1], CSC, mbv[ct]));
            float p2 = __builtin_amdgcn_exp2f(fmaf(sacc[ct][2], CSC, mbv[ct]));
            float p3 = __builtin_amdgcn_exp2f(fmaf(sacc[ct][3], CSC, mbv[ct]));
            lpart[0] += p0; lpart[1] += p1; lpart[2] += p2; lpart[3] += p3;
            unsigned u01 = cvt_pk_bf16(p0, p1);
            unsigned u23 = cvt_pk_bf16(p2, p3);
            int base = (w * 16 + l4 * 4) * 72 + ct * 16 + l15;
            Ps[base]       = (ushort_t)u01;
            Ps[base + 72]  = (ushort_t)(u01 >> 16);
            Ps[base + 144] = (ushort_t)u23;
            Ps[base + 216] = (ushort_t)(u23 >> 16);
        }

#pragma unroll
        for (int ks = 0; ks < 2; ++ks) {
            s16x8 af = *(const s16x8*)&Ps[(w * 16 + l15) * 72 + ks * 32 + l4 * 8];
#pragma unroll
            for (int dt = 0; dt < 4; ++dt) {
                s16x8 bf = *(const s16x8*)&Vs[(dt * 16 + l15) * 72 + ks * 32 + l4 * 8];
                oacc[dt] = __builtin_amdgcn_mfma_f32_16x16x32_bf16(af, bf, oacc[dt], 0, 0, 0);
            }
        }
    }

#pragma unroll
    for (int r = 0; r < 4; ++r) {
        lpart[r] += __shfl_xor(lpart[r], 1);
        lpart[r] += __shfl_xor(lpart[r], 2);
        lpart[r] += __shfl_xor(lpart[r], 4);
        lpart[r] += __shfl_xor(lpart[r], 8);
    }
    const size_t obase = ((size_t)b * SEQ + q0 + w * 16 + l4 * 4) * D_MODEL + h * DKH + l15;
#pragma unroll
    for (int r = 0; r < 4; ++r) {
        float inv = 1.f / lpart[r];
#pragma unroll
        for (int dt = 0; dt < 4; ++dt)
            Ctx[obase + (size_t)r * D_MODEL + dt * 16] = f2bf(oacc[dt][r] * inv);
    }
}

extern "C" void kernel_launch(void* const* d_in, const int* in_sizes, int n_in,
                              void* d_out, int out_size, void* d_ws, size_t ws_size,
                              hipStream_t stream) {
    const float* q    = (const float*)d_in[0];
    const float* k    = (const float*)d_in[1];
    const float* v    = (const float*)d_in[2];
    const int*   mask = (const int*)  d_in[3];
    const float* Wq   = (const float*)d_in[4];
    const float* bq   = (const float*)d_in[5];
    const float* Wk   = (const float*)d_in[6];
    const float* bk   = (const float*)d_in[7];
    const float* Wv   = (const float*)d_in[8];
    const float* bv   = (const float*)d_in[9];
    const float* Wo   = (const float*)d_in[10];
    const float* bo   = (const float*)d_in[11];
    float* out = (float*)d_out;

    char* ws = (char*)d_ws;
    ushort_t* Wqb  = (ushort_t*)(ws);
    ushort_t* Wkb  = (ushort_t*)(ws + ( 2u << 20));
    ushort_t* Wvb  = (ushort_t*)(ws + ( 4u << 20));
    ushort_t* Wohi = (ushort_t*)(ws + ( 6u << 20));
    ushort_t* Wolo = (ushort_t*)(ws + ( 8u << 20));
    float*    mb   = (float*)   (ws + (10u << 20));
    ushort_t* Qb   = (ushort_t*)(ws + (12u << 20));
    ushort_t* Kb   = (ushort_t*)(ws + (20u << 20));
    ushort_t* Vtb  = (ushort_t*)(ws + (28u << 20));
    ushort_t* Ctx  = (ushort_t*)(ws + (36u << 20));

    convert_w<<<1024, 256, 0, stream>>>(Wq, Wk, Wv, Wo, mask,
                                        Wqb, Wkb, Wvb, Wohi, Wolo, mb);

    dim3 ggrid(D_MODEL / 128, TOK / 128);
    gemm3<1, 0, 0><<<ggrid, 256, 0, stream>>>(q, Wqb, nullptr, bq, Qb);
    gemm3<1, 0, 0><<<ggrid, 256, 0, stream>>>(k, Wkb, nullptr, bk, Kb);
    gemm3<1, 2, 0><<<ggrid, 256, 0, stream>>>(v, Wvb, nullptr, bv, Vtb);

    dim3 agrid(SEQ / 64, BATCH * NHEAD);
    flash2<<<agrid, 256, 0, stream>>>(Qb, Kb, Vtb, mb, Ctx);

    gemm3<0, 1, 1><<<ggrid, 256, 0, stream>>>(Ctx, Wohi, Wolo, bo, out);
}